// Round 1
// baseline (1961.208 us; speedup 1.0000x reference)
//
#include <hip/hip_runtime.h>
#include <cstdint>
#include <cstddef>

static __device__ __forceinline__ float elu_f(float t) {
    return t > 0.0f ? t : expm1f(t);
}

// Gathered GEMM: out[m, n] = elu( sum_k A[m,k] * W[k,n] + bias[n] )
// A[m,k] = x[b, spiral[v, s], c]  with m = b*V + v, k = s*C_IN + c
template<int C_IN, int C_OUT, int BM, int BN, int BK, int TM, int TN>
__global__ __launch_bounds__((BM/TM)*(BN/TN))
void conv_kernel(const float* __restrict__ x, const int* __restrict__ spiral,
                 const float* __restrict__ W, const float* __restrict__ bias,
                 float* __restrict__ out, int vshift)
{
    constexpr int NT = (BM/TM)*(BN/TN);
    constexpr int K  = 12*C_IN;
    constexpr int NTHR_N = BN/TN;
    __shared__ float As[BK][BM+4];
    __shared__ float Ws[BK][BN];

    const int vmask = (1 << vshift) - 1;
    const int tid = threadIdx.x;
    const int m0 = blockIdx.x * BM;
    const int n0 = blockIdx.y * BN;
    const int n_idx = tid % NTHR_N;
    const int m_idx = tid / NTHR_N;
    const int row0 = m_idx * TM;
    const int col0 = n_idx * TN;

    float acc[TM][TN];
    #pragma unroll
    for (int i = 0; i < TM; ++i)
        #pragma unroll
        for (int j = 0; j < TN; ++j) acc[i][j] = 0.0f;

    for (int kt = 0; kt < K; kt += BK) {
        // ---- A tile (gathered) ----
        #pragma unroll
        for (int e = tid; e < BM*BK; e += NT) {
            int ml = e / BK, kk = e % BK;
            int m = m0 + ml;
            int b = m >> vshift;
            int v = m & vmask;
            int kg = kt + kk;
            int s = kg / C_IN, c = kg % C_IN;
            int idx = spiral[v*12 + s];
            As[kk][ml] = x[(size_t)(((b << vshift) + idx) * C_IN + c)];
        }
        // ---- W tile ----
        for (int e = tid; e < BK*BN; e += NT) {
            int kk = e / BN, n = e % BN;
            Ws[kk][n] = W[(size_t)(kt + kk)*C_OUT + n0 + n];
        }
        __syncthreads();
        #pragma unroll
        for (int kk = 0; kk < BK; ++kk) {
            float a[TM], wv[TN];
            #pragma unroll
            for (int i = 0; i < TM; ++i) a[i] = As[kk][row0 + i];
            #pragma unroll
            for (int j = 0; j < TN; ++j) wv[j] = Ws[kk][col0 + j];
            #pragma unroll
            for (int i = 0; i < TM; ++i)
                #pragma unroll
                for (int j = 0; j < TN; ++j) acc[i][j] += a[i]*wv[j];
        }
        __syncthreads();
    }

    #pragma unroll
    for (int i = 0; i < TM; ++i) {
        int m = m0 + row0 + i;
        #pragma unroll
        for (int j = 0; j < TN; ++j) {
            int n = n0 + col0 + j;
            out[(size_t)m*C_OUT + n] = elu_f(acc[i][j] + bias[n]);
        }
    }
}

// out[b, v, c] = sum_{k<3} dw[v,k] * in[b, didx[v,k], c]
__global__ __launch_bounds__(256)
void pool_kernel(const float* __restrict__ in, const int* __restrict__ didx,
                 const float* __restrict__ dw, float* __restrict__ out,
                 int vishift, int voshift, int cshift, int total)
{
    int i = blockIdx.x * blockDim.x + threadIdx.x;
    if (i >= total) return;
    int cmask = (1 << cshift) - 1;
    int vomask = (1 << voshift) - 1;
    int c = i & cmask;
    int t = i >> cshift;
    int v = t & vomask;
    int b = t >> voshift;
    const int* di = didx + v*3;
    const float* w = dw + v*3;
    int base = b << vishift;
    float s = w[0] * in[((size_t)(base + di[0]) << cshift) + c]
            + w[1] * in[((size_t)(base + di[1]) << cshift) + c]
            + w[2] * in[((size_t)(base + di[2]) << cshift) + c];
    out[i] = s;
}

// FC1 split-K partial: grid (8 n-tiles of 64, 64 k-chunks of 512), block 256.
__global__ __launch_bounds__(256)
void fc1_partial(const float* __restrict__ xflat, const float* __restrict__ Wl1,
                 float* __restrict__ acc_out)
{
    __shared__ float xs[32][68];
    const int tid = threadIdx.x;
    const int n  = blockIdx.x * 64 + (tid & 63);
    const int mg = tid >> 6;           // 0..3, 8 m-rows each
    const int kbase = blockIdx.y * 512;

    float acc[8];
    #pragma unroll
    for (int i = 0; i < 8; ++i) acc[i] = 0.0f;

    for (int kt = 0; kt < 512; kt += 64) {
        for (int e = tid; e < 32*64; e += 256) {
            int m = e >> 6, k = e & 63;
            xs[m][k] = xflat[(size_t)m*32768 + kbase + kt + k];
        }
        __syncthreads();
        for (int k = 0; k < 64; k += 4) {
            float wv[4];
            #pragma unroll
            for (int j = 0; j < 4; ++j)
                wv[j] = Wl1[(size_t)(kbase + kt + k + j)*512 + n];
            #pragma unroll
            for (int i = 0; i < 8; ++i) {
                float4 xv = *(const float4*)&xs[mg*8 + i][k];
                acc[i] += xv.x*wv[0] + xv.y*wv[1] + xv.z*wv[2] + xv.w*wv[3];
            }
        }
        __syncthreads();
    }
    #pragma unroll
    for (int i = 0; i < 8; ++i)
        atomicAdd(&acc_out[(size_t)(mg*8 + i)*512 + n], acc[i]);
}

__global__ __launch_bounds__(256)
void fc1_finish(const float* __restrict__ acc, const float* __restrict__ bl1,
                float* __restrict__ hout)
{
    int i = blockIdx.x * blockDim.x + threadIdx.x;   // 16384 total
    float t = acc[i] + bl1[i & 511];
    hout[i] = elu_f(t);
}

// y[m, n] = sum_k h[m,k] * Wl2[k,n] + bl2[n];  grid 32 (m), block 64 (n)
__global__ __launch_bounds__(64)
void fc2_kernel(const float* __restrict__ h, const float* __restrict__ Wl2,
                const float* __restrict__ bl2, float* __restrict__ y)
{
    int m = blockIdx.x;
    int n = threadIdx.x;
    float s = bl2[n];
    for (int k = 0; k < 512; ++k)
        s += h[(size_t)m*512 + k] * Wl2[(size_t)k*64 + n];
    y[(size_t)m*64 + n] = s;
}

extern "C" void kernel_launch(void* const* d_in, const int* in_sizes, int n_in,
                              void* d_out, int out_size, void* d_ws, size_t ws_size,
                              hipStream_t stream)
{
    (void)in_sizes; (void)n_in; (void)out_size;

    const float* x0 = (const float*)d_in[0];
    const int*   sp[4]; const int* didx[4]; const float* dwp[4];
    const float* Wp[4]; const float* bp[4];
    for (int i = 0; i < 4; ++i) {
        sp[i]   = (const int*)  d_in[1 + i*5 + 0];
        didx[i] = (const int*)  d_in[1 + i*5 + 1];
        dwp[i]  = (const float*)d_in[1 + i*5 + 2];
        Wp[i]   = (const float*)d_in[1 + i*5 + 3];
        bp[i]   = (const float*)d_in[1 + i*5 + 4];
    }
    const float* Wl1 = (const float*)d_in[21];
    const float* bl1 = (const float*)d_in[22];
    const float* Wl2 = (const float*)d_in[23];
    const float* bl2 = (const float*)d_in[24];
    float* out = (float*)d_out;

    float* ws = (float*)d_ws;
    float* persist = ws;                       // 1,048,576 floats: (32,128,256) flat
    float* fc1_acc = ws + 1048576;             // 16,384 floats
    float* regA    = ws + 1048576 + 16384;

    size_t avail_floats = ws_size / 4;
    int Bc = 32;
    while (Bc > 1 &&
           (size_t)(1048576 + 16384) + (size_t)Bc*1310720ULL > avail_floats)
        Bc >>= 1;
    float* regB = regA + (size_t)Bc*1048576ULL;

    hipMemsetAsync(fc1_acc, 0, 16384*sizeof(float), stream);

    for (int b0 = 0; b0 < 32; b0 += Bc) {
        const float* xin = x0 + (size_t)b0*32768*3;

        // Level 0: V=32768, 3->32, K=36
        conv_kernel<3,32,128,32,36,8,2>
            <<<dim3(Bc*32768/128, 1), 256, 0, stream>>>(xin, sp[0], Wp[0], bp[0], regA, 15);
        pool_kernel<<<(Bc*8192*32 + 255)/256, 256, 0, stream>>>(
            regA, didx[0], dwp[0], regB, 15, 13, 5, Bc*8192*32);

        // Level 1: V=8192, 32->64, K=384
        conv_kernel<32,64,128,64,32,8,4>
            <<<dim3(Bc*8192/128, 1), 256, 0, stream>>>(regB, sp[1], Wp[1], bp[1], regA, 13);
        pool_kernel<<<(Bc*2048*64 + 255)/256, 256, 0, stream>>>(
            regA, didx[1], dwp[1], regB, 13, 11, 6, Bc*2048*64);

        // Level 2: V=2048, 64->128, K=768
        conv_kernel<64,128,128,128,32,8,8>
            <<<dim3(Bc*2048/128, 1), 256, 0, stream>>>(regB, sp[2], Wp[2], bp[2], regA, 11);
        pool_kernel<<<(Bc*512*128 + 255)/256, 256, 0, stream>>>(
            regA, didx[2], dwp[2], regB, 11, 9, 7, Bc*512*128);

        // Level 3: V=512, 128->256, K=1536
        conv_kernel<128,256,128,128,32,8,8>
            <<<dim3(Bc*512/128, 2), 256, 0, stream>>>(regB, sp[3], Wp[3], bp[3], regA, 9);
        pool_kernel<<<(Bc*128*256 + 255)/256, 256, 0, stream>>>(
            regA, didx[3], dwp[3], persist + (size_t)b0*32768, 9, 7, 8, Bc*128*256);
    }

    // FC1: (32, 32768) @ (32768, 512) + bias, ELU -> d_out[0:16384]
    fc1_partial<<<dim3(8, 64), 256, 0, stream>>>(persist, Wl1, fc1_acc);
    fc1_finish<<<64, 256, 0, stream>>>(fc1_acc, bl1, out);

    // FC2: (32, 512) @ (512, 64) + bias -> d_out[16384:18432]
    fc2_kernel<<<32, 64, 0, stream>>>(out, Wl2, bl2, out + 16384);
}

// Round 2
// 751.678 us; speedup vs baseline: 2.6091x; 2.6091x over previous
//
#include <hip/hip_runtime.h>
#include <cstdint>
#include <cstddef>

typedef _Float16 f16x8 __attribute__((ext_vector_type(8)));
typedef float f32x4 __attribute__((ext_vector_type(4)));

static __device__ __forceinline__ float elu_f(float t) {
    return t > 0.0f ? t : expm1f(t);
}

// ---------------- fp32 conv (kept for level 0: C_IN=3, K=36) ----------------
template<int C_IN, int C_OUT, int BM, int BN, int BK, int TM, int TN>
__global__ __launch_bounds__((BM/TM)*(BN/TN))
void conv_kernel(const float* __restrict__ x, const int* __restrict__ spiral,
                 const float* __restrict__ W, const float* __restrict__ bias,
                 float* __restrict__ out, int vshift)
{
    constexpr int NT = (BM/TM)*(BN/TN);
    constexpr int K  = 12*C_IN;
    constexpr int NTHR_N = BN/TN;
    __shared__ float As[BK][BM+4];
    __shared__ float Ws[BK][BN];

    const int vmask = (1 << vshift) - 1;
    const int tid = threadIdx.x;
    const int m0 = blockIdx.x * BM;
    const int n0 = blockIdx.y * BN;
    const int n_idx = tid % NTHR_N;
    const int m_idx = tid / NTHR_N;
    const int row0 = m_idx * TM;
    const int col0 = n_idx * TN;

    float acc[TM][TN];
    #pragma unroll
    for (int i = 0; i < TM; ++i)
        #pragma unroll
        for (int j = 0; j < TN; ++j) acc[i][j] = 0.0f;

    for (int kt = 0; kt < K; kt += BK) {
        #pragma unroll
        for (int e = tid; e < BM*BK; e += NT) {
            int ml = e / BK, kk = e % BK;
            int m = m0 + ml;
            int b = m >> vshift;
            int v = m & vmask;
            int kg = kt + kk;
            int s = kg / C_IN, c = kg % C_IN;
            int idx = spiral[v*12 + s];
            As[kk][ml] = x[(size_t)(((b << vshift) + idx) * C_IN + c)];
        }
        for (int e = tid; e < BK*BN; e += NT) {
            int kk = e / BN, n = e % BN;
            Ws[kk][n] = W[(size_t)(kt + kk)*C_OUT + n0 + n];
        }
        __syncthreads();
        #pragma unroll
        for (int kk = 0; kk < BK; ++kk) {
            float a[TM], wv[TN];
            #pragma unroll
            for (int i = 0; i < TM; ++i) a[i] = As[kk][row0 + i];
            #pragma unroll
            for (int j = 0; j < TN; ++j) wv[j] = Ws[kk][col0 + j];
            #pragma unroll
            for (int i = 0; i < TM; ++i)
                #pragma unroll
                for (int j = 0; j < TN; ++j) acc[i][j] += a[i]*wv[j];
        }
        __syncthreads();
    }

    #pragma unroll
    for (int i = 0; i < TM; ++i) {
        int m = m0 + row0 + i;
        #pragma unroll
        for (int j = 0; j < TN; ++j) {
            int n = n0 + col0 + j;
            out[(size_t)m*C_OUT + n] = elu_f(acc[i][j] + bias[n]);
        }
    }
}

// ---------------- weight prep: fp32 [K][C_OUT] -> fp16 tiled [y][t][kc][n][8] ----------------
template<int KTOT, int C_OUT, int BN>
__global__ __launch_bounds__(256)
void prep_w(const float* __restrict__ W, _Float16* __restrict__ o)
{
    constexpr int KT = KTOT/64;
    int i = blockIdx.x * 256 + threadIdx.x;
    if (i >= KTOT*C_OUT) return;
    int j = i & 7;
    int rest = i >> 3;
    int n = rest % BN;
    int kc = (rest / BN) & 7;
    int t = (rest / (BN*8)) % KT;
    int y = rest / (BN*8*KT);
    int k = t*64 + kc*8 + j;
    o[i] = (_Float16)W[(size_t)k*C_OUT + y*BN + n];
}

// ---------------- fp16 MFMA conv (levels 1-3) ----------------
// out[m,n] = elu( sum_k A[m,k]*W[k,n] + bias[n] ),  A gathered via spiral.
// Wp is pre-transposed fp16 in exact LDS tile order (see prep_w).
template<int C_IN, int C_OUT, int BM, int BN, int WGM, int WGN>
__global__ __launch_bounds__(256)
void conv_mfma(const float* __restrict__ x, const int* __restrict__ spiral,
               const _Float16* __restrict__ Wp, const float* __restrict__ bias,
               float* __restrict__ out, int vshift)
{
    constexpr int BK   = 64;
    constexpr int KTOT = 12*C_IN;
    constexpr int KT   = KTOT/BK;
    constexpr int WTM  = BM/WGM;   // 64
    constexpr int WTN  = BN/WGN;   // 64
    constexpr int NMT  = WTM/16;   // 4
    constexpr int NNT  = WTN/16;   // 4

    __shared__ _Float16 As[64*BM];   // [kc 0..7][m 0..BM-1][8]
    __shared__ _Float16 Ws[64*BN];   // [kc 0..7][n 0..BN-1][8]

    const int tid  = threadIdx.x;
    const int wave = tid >> 6;
    const int lane = tid & 63;
    const int quad = lane >> 4;
    const int l16  = lane & 15;
    const int wm   = wave / WGN;
    const int wn   = wave % WGN;
    const int m0   = blockIdx.x * BM;
    const int n0   = blockIdx.y * BN;
    const int vmask = (1 << vshift) - 1;

    f32x4 acc[NMT][NNT];
    #pragma unroll
    for (int i = 0; i < NMT; ++i)
        #pragma unroll
        for (int j = 0; j < NNT; ++j) acc[i][j] = (f32x4){0.f, 0.f, 0.f, 0.f};

    for (int t = 0; t < KT; ++t) {
        // ---- stage A: gather + fp16 convert, chunk-major [kc][m][8] ----
        #pragma unroll 2
        for (int e = tid; e < BM*8; e += 256) {
            int m  = e >> 3;
            int kc = e & 7;
            int mm = m0 + m;
            int b  = mm >> vshift;
            int v  = mm & vmask;
            int k  = t*64 + kc*8;
            int s  = k / C_IN;
            int c  = k & (C_IN - 1);
            int g  = spiral[v*12 + s];
            const float* src = x + ((size_t)((b << vshift) + g) * C_IN + c);
            float4 p0 = *(const float4*)(src);
            float4 p1 = *(const float4*)(src + 4);
            f16x8 h;
            h[0] = (_Float16)p0.x; h[1] = (_Float16)p0.y;
            h[2] = (_Float16)p0.z; h[3] = (_Float16)p0.w;
            h[4] = (_Float16)p1.x; h[5] = (_Float16)p1.y;
            h[6] = (_Float16)p1.z; h[7] = (_Float16)p1.w;
            *(f16x8*)&As[(kc*BM + m)*8] = h;
        }
        // ---- stage W: flat coalesced copy of this (y, t) tile ----
        {
            const _Float16* wsrc = Wp + ((size_t)(blockIdx.y*KT + t)) * (64*BN);
            #pragma unroll 2
            for (int e = tid; e < BN*8; e += 256)
                *(f16x8*)&Ws[e*8] = *(const f16x8*)&wsrc[e*8];
        }
        __syncthreads();

        #pragma unroll
        for (int kt = 0; kt < 2; ++kt) {       // two K=32 steps per tile
            f16x8 af[NMT], bf[NNT];
            #pragma unroll
            for (int i = 0; i < NMT; ++i) {
                int m_local = wm*WTM + i*16 + l16;
                af[i] = *(const f16x8*)&As[((kt*4 + quad)*BM + m_local)*8];
            }
            #pragma unroll
            for (int j = 0; j < NNT; ++j) {
                int n_local = wn*WTN + j*16 + l16;
                bf[j] = *(const f16x8*)&Ws[((kt*4 + quad)*BN + n_local)*8];
            }
            #pragma unroll
            for (int i = 0; i < NMT; ++i)
                #pragma unroll
                for (int j = 0; j < NNT; ++j)
                    acc[i][j] = __builtin_amdgcn_mfma_f32_16x16x32_f16(
                        af[i], bf[j], acc[i][j], 0, 0, 0);
        }
        __syncthreads();
    }

    // ---- epilogue: bias + ELU + store (C/D: col=lane&15, row=quad*4+reg) ----
    float bv[NNT];
    #pragma unroll
    for (int j = 0; j < NNT; ++j)
        bv[j] = bias[n0 + wn*WTN + j*16 + l16];

    #pragma unroll
    for (int i = 0; i < NMT; ++i) {
        int row_base = m0 + wm*WTM + i*16 + quad*4;
        #pragma unroll
        for (int j = 0; j < NNT; ++j) {
            int col = n0 + wn*WTN + j*16 + l16;
            #pragma unroll
            for (int r = 0; r < 4; ++r) {
                out[(size_t)(row_base + r)*C_OUT + col] = elu_f(acc[i][j][r] + bv[j]);
            }
        }
    }
}

// ---------------- pool: out[b,v,c] = sum_k dw[v,k]*in[b,didx[v,k],c] ----------------
__global__ __launch_bounds__(256)
void pool_kernel(const float* __restrict__ in, const int* __restrict__ didx,
                 const float* __restrict__ dw, float* __restrict__ out,
                 int vishift, int voshift, int cshift, int total)
{
    int i = blockIdx.x * blockDim.x + threadIdx.x;
    if (i >= total) return;
    int cmask = (1 << cshift) - 1;
    int vomask = (1 << voshift) - 1;
    int c = i & cmask;
    int t = i >> cshift;
    int v = t & vomask;
    int b = t >> voshift;
    const int* di = didx + v*3;
    const float* w = dw + v*3;
    int base = b << vishift;
    float s = w[0] * in[((size_t)(base + di[0]) << cshift) + c]
            + w[1] * in[((size_t)(base + di[1]) << cshift) + c]
            + w[2] * in[((size_t)(base + di[2]) << cshift) + c];
    out[i] = s;
}

// ---------------- FC1 split-K + finish, FC2 ----------------
__global__ __launch_bounds__(256)
void fc1_partial(const float* __restrict__ xflat, const float* __restrict__ Wl1,
                 float* __restrict__ acc_out)
{
    __shared__ float xs[32][68];
    const int tid = threadIdx.x;
    const int n  = blockIdx.x * 64 + (tid & 63);
    const int mg = tid >> 6;
    const int kbase = blockIdx.y * 512;

    float acc[8];
    #pragma unroll
    for (int i = 0; i < 8; ++i) acc[i] = 0.0f;

    for (int kt = 0; kt < 512; kt += 64) {
        for (int e = tid; e < 32*64; e += 256) {
            int m = e >> 6, k = e & 63;
            xs[m][k] = xflat[(size_t)m*32768 + kbase + kt + k];
        }
        __syncthreads();
        for (int k = 0; k < 64; k += 4) {
            float wv[4];
            #pragma unroll
            for (int j = 0; j < 4; ++j)
                wv[j] = Wl1[(size_t)(kbase + kt + k + j)*512 + n];
            #pragma unroll
            for (int i = 0; i < 8; ++i) {
                float4 xv = *(const float4*)&xs[mg*8 + i][k];
                acc[i] += xv.x*wv[0] + xv.y*wv[1] + xv.z*wv[2] + xv.w*wv[3];
            }
        }
        __syncthreads();
    }
    #pragma unroll
    for (int i = 0; i < 8; ++i)
        atomicAdd(&acc_out[(size_t)(mg*8 + i)*512 + n], acc[i]);
}

__global__ __launch_bounds__(256)
void fc1_finish(const float* __restrict__ acc, const float* __restrict__ bl1,
                float* __restrict__ hout)
{
    int i = blockIdx.x * blockDim.x + threadIdx.x;
    float t = acc[i] + bl1[i & 511];
    hout[i] = elu_f(t);
}

__global__ __launch_bounds__(64)
void fc2_kernel(const float* __restrict__ h, const float* __restrict__ Wl2,
                const float* __restrict__ bl2, float* __restrict__ y)
{
    int m = blockIdx.x;
    int n = threadIdx.x;
    float s = bl2[n];
    for (int k = 0; k < 512; ++k)
        s += h[(size_t)m*512 + k] * Wl2[(size_t)k*64 + n];
    y[(size_t)m*64 + n] = s;
}

extern "C" void kernel_launch(void* const* d_in, const int* in_sizes, int n_in,
                              void* d_out, int out_size, void* d_ws, size_t ws_size,
                              hipStream_t stream)
{
    (void)in_sizes; (void)n_in; (void)out_size;

    const float* x0 = (const float*)d_in[0];
    const int*   sp[4]; const int* didx[4]; const float* dwp[4];
    const float* Wp[4]; const float* bp[4];
    for (int i = 0; i < 4; ++i) {
        sp[i]   = (const int*)  d_in[1 + i*5 + 0];
        didx[i] = (const int*)  d_in[1 + i*5 + 1];
        dwp[i]  = (const float*)d_in[1 + i*5 + 2];
        Wp[i]   = (const float*)d_in[1 + i*5 + 3];
        bp[i]   = (const float*)d_in[1 + i*5 + 4];
    }
    const float* Wl1 = (const float*)d_in[21];
    const float* bl1 = (const float*)d_in[22];
    const float* Wl2 = (const float*)d_in[23];
    const float* bl2 = (const float*)d_in[24];
    float* out = (float*)d_out;

    float* ws = (float*)d_ws;
    float* persist = ws;                       // 1,048,576 floats: (32,128,256) flat
    float* fc1_acc = ws + 1048576;             // 16,384 floats
    _Float16* w1h  = (_Float16*)(ws + 1048576 + 16384);   // 24576 halfs
    _Float16* w2h  = w1h + 24576;                          // 98304 halfs
    _Float16* w3h  = w2h + 98304;                          // 393216 halfs
    float* regA    = ws + 1048576 + 16384 + 262144;

    size_t avail_floats = ws_size / 4;
    const size_t fixed = 1048576 + 16384 + 262144;
    int Bc = 32;
    while (Bc > 1 && fixed + (size_t)Bc*1310720ULL > avail_floats)
        Bc >>= 1;
    float* regB = regA + (size_t)Bc*1048576ULL;

    // Per-launch weight prep (fp32 -> fp16, transposed into LDS tile order)
    prep_w< 384,  64,  64><<<( 24576 + 255)/256, 256, 0, stream>>>(Wp[1], w1h);
    prep_w< 768, 128, 128><<<( 98304 + 255)/256, 256, 0, stream>>>(Wp[2], w2h);
    prep_w<1536, 256, 128><<<(393216 + 255)/256, 256, 0, stream>>>(Wp[3], w3h);

    hipMemsetAsync(fc1_acc, 0, 16384*sizeof(float), stream);

    for (int b0 = 0; b0 < 32; b0 += Bc) {
        const float* xin = x0 + (size_t)b0*32768*3;

        // Level 0: V=32768, 3->32, K=36 (fp32 path)
        conv_kernel<3,32,128,32,36,8,2>
            <<<dim3(Bc*32768/128, 1), 256, 0, stream>>>(xin, sp[0], Wp[0], bp[0], regA, 15);
        pool_kernel<<<(Bc*8192*32 + 255)/256, 256, 0, stream>>>(
            regA, didx[0], dwp[0], regB, 15, 13, 5, Bc*8192*32);

        // Level 1: V=8192, 32->64, K=384 (MFMA fp16): BM=256, BN=64
        conv_mfma<32,64,256,64,4,1>
            <<<dim3(Bc*8192/256, 1), 256, 0, stream>>>(regB, sp[1], w1h, bp[1], regA, 13);
        pool_kernel<<<(Bc*2048*64 + 255)/256, 256, 0, stream>>>(
            regA, didx[1], dwp[1], regB, 13, 11, 6, Bc*2048*64);

        // Level 2: V=2048, 64->128, K=768 (MFMA fp16): BM=128, BN=128
        conv_mfma<64,128,128,128,2,2>
            <<<dim3(Bc*2048/128, 1), 256, 0, stream>>>(regB, sp[2], w2h, bp[2], regA, 11);
        pool_kernel<<<(Bc*512*128 + 255)/256, 256, 0, stream>>>(
            regA, didx[2], dwp[2], regB, 11, 9, 7, Bc*512*128);

        // Level 3: V=512, 128->256, K=1536 (MFMA fp16): BM=128, BN=128, y=2
        conv_mfma<128,256,128,128,2,2>
            <<<dim3(Bc*512/128, 2), 256, 0, stream>>>(regB, sp[3], w3h, bp[3], regA, 9);
        pool_kernel<<<(Bc*128*256 + 255)/256, 256, 0, stream>>>(
            regA, didx[3], dwp[3], persist + (size_t)b0*32768, 9, 7, 8, Bc*128*256);
    }

    // FC1: (32, 32768) @ (32768, 512) + bias, ELU -> d_out[0:16384]
    fc1_partial<<<dim3(8, 64), 256, 0, stream>>>(persist, Wl1, fc1_acc);
    fc1_finish<<<64, 256, 0, stream>>>(fc1_acc, bl1, out);

    // FC2: (32, 512) @ (512, 64) + bias -> d_out[16384:18432]
    fc2_kernel<<<32, 64, 0, stream>>>(out, Wl2, bl2, out + 16384);
}

// Round 3
// 530.614 us; speedup vs baseline: 3.6961x; 1.4166x over previous
//
#include <hip/hip_runtime.h>
#include <cstdint>
#include <cstddef>

typedef _Float16 f16x8 __attribute__((ext_vector_type(8)));
typedef float f32x4 __attribute__((ext_vector_type(4)));

static __device__ __forceinline__ float elu_f(float t) {
    return t > 0.0f ? t : expm1f(t);
}

// ---------------- weight prep: fp32 [K][C_OUT] -> fp16 tiled [y][t][kc][n][8] ----------------
template<int KTOT, int C_OUT, int BN>
__global__ __launch_bounds__(256)
void prep_w(const float* __restrict__ W, _Float16* __restrict__ o)
{
    constexpr int KT = KTOT/64;
    int i = blockIdx.x * 256 + threadIdx.x;
    if (i >= KTOT*C_OUT) return;
    int j = i & 7;
    int rest = i >> 3;
    int n = rest % BN;
    int kc = (rest / BN) & 7;
    int t = (rest / (BN*8)) % KT;
    int y = rest / (BN*8*KT);
    int k = t*64 + kc*8 + j;
    o[i] = (_Float16)W[(size_t)k*C_OUT + y*BN + n];
}

// Level-0 weights: W0 is (36, 32); pad K to 64 with layout k = s*4 + c (c<3 real).
// Tile order [kc][n][8], 2048 halfs total.
__global__ __launch_bounds__(256)
void prep_w0(const float* __restrict__ W, _Float16* __restrict__ o)
{
    int i = blockIdx.x * 256 + threadIdx.x;
    if (i >= 2048) return;
    int j = i & 7;
    int n = (i >> 3) & 31;
    int kc = i >> 8;
    int k = kc*8 + j;
    int s = k >> 2, c = k & 3;
    float v = (s < 12 && c < 3) ? W[(size_t)(s*3 + c)*32 + n] : 0.0f;
    o[i] = (_Float16)v;
}

// ---------------- fused conv+pool, MFMA fp16, levels 1-3 ----------------
// Block owns P pooled vertices -> computes R=3P gathered conv rows on demand,
// then combines triples with dw into pooled output. x: (B, V_in, C_IN).
template<int C_IN, int C_OUT, int P, int BN, int WGM, int WGN>
__global__ __launch_bounds__(256)
void conv_pool_mfma(const float* __restrict__ x, const int* __restrict__ spiral,
                    const _Float16* __restrict__ Wp, const float* __restrict__ bias,
                    const int* __restrict__ didx, const float* __restrict__ dwt,
                    float* __restrict__ out, int vshift_in, int vshift_out)
{
    constexpr int R    = 3*P;
    constexpr int KTOT = 12*C_IN;
    constexpr int KT   = KTOT/64;
    constexpr int WTM  = R/WGM;
    constexpr int WTN  = BN/WGN;
    constexpr int NMT  = WTM/16;
    constexpr int NNT  = WTN/16;
    constexpr int C4   = BN/4;
    constexpr int STAGE_B = 64*R*2 + 64*BN*2;
    constexpr int EPI_B   = R*(BN+4)*4;
    constexpr int SMEM_B  = STAGE_B > EPI_B ? STAGE_B : EPI_B;
    static_assert(WTM % 16 == 0 && WTN % 16 == 0, "tile");
    static_assert((R*8) % 256 == 0 && (P*C4) % 256 == 0, "loops");

    __shared__ char smem[SMEM_B] __attribute__((aligned(16)));
    _Float16* As = (_Float16*)smem;
    _Float16* Ws = As + 64*R;

    const int tid  = threadIdx.x;
    const int wave = tid >> 6;
    const int lane = tid & 63;
    const int quad = lane >> 4;
    const int l16  = lane & 15;
    const int wm   = wave / WGN;
    const int wn   = wave % WGN;
    const int pu0  = blockIdx.x * P;
    const int n0   = blockIdx.y * BN;
    const int vmask_out = (1 << vshift_out) - 1;

    f32x4 acc[NMT][NNT];
    #pragma unroll
    for (int i = 0; i < NMT; ++i)
        #pragma unroll
        for (int j = 0; j < NNT; ++j) acc[i][j] = (f32x4){0.f, 0.f, 0.f, 0.f};

    for (int t = 0; t < KT; ++t) {
        // ---- stage A: double-indirect gather + fp16 convert, [kc][row][8] ----
        #pragma unroll
        for (int e = tid; e < R*8; e += 256) {
            int r  = e >> 3;
            int kc = e & 7;
            int ul = r / 3;
            int kp = r - ul*3;
            int pu = pu0 + ul;
            int b  = pu >> vshift_out;
            int u  = pu & vmask_out;
            int v  = didx[u*3 + kp];
            int k  = t*64 + kc*8;
            int s  = k / C_IN;
            int c  = k & (C_IN - 1);
            int g  = spiral[v*12 + s];
            const float* src = x + ((size_t)(((size_t)b << vshift_in) + g)*C_IN + c);
            float4 p0 = *(const float4*)(src);
            float4 p1 = *(const float4*)(src + 4);
            f16x8 h;
            h[0] = (_Float16)p0.x; h[1] = (_Float16)p0.y;
            h[2] = (_Float16)p0.z; h[3] = (_Float16)p0.w;
            h[4] = (_Float16)p1.x; h[5] = (_Float16)p1.y;
            h[6] = (_Float16)p1.z; h[7] = (_Float16)p1.w;
            *(f16x8*)&As[(kc*R + r)*8] = h;
        }
        // ---- stage W: flat coalesced copy of this (y, t) tile ----
        {
            const _Float16* wsrc = Wp + (size_t)(blockIdx.y*KT + t)*(64*BN);
            #pragma unroll
            for (int e = tid; e < BN*8; e += 256)
                *(f16x8*)&Ws[e*8] = *(const f16x8*)&wsrc[e*8];
        }
        __syncthreads();

        #pragma unroll
        for (int kt = 0; kt < 2; ++kt) {
            f16x8 af[NMT], bf[NNT];
            #pragma unroll
            for (int i = 0; i < NMT; ++i) {
                int m_local = wm*WTM + i*16 + l16;
                af[i] = *(const f16x8*)&As[((kt*4 + quad)*R + m_local)*8];
            }
            #pragma unroll
            for (int j = 0; j < NNT; ++j) {
                int n_local = wn*WTN + j*16 + l16;
                bf[j] = *(const f16x8*)&Ws[((kt*4 + quad)*BN + n_local)*8];
            }
            #pragma unroll
            for (int i = 0; i < NMT; ++i)
                #pragma unroll
                for (int j = 0; j < NNT; ++j)
                    acc[i][j] = __builtin_amdgcn_mfma_f32_16x16x32_f16(
                        af[i], bf[j], acc[i][j], 0, 0, 0);
        }
        __syncthreads();
    }

    // ---- epilogue: bias+ELU conv rows into LDS (reuse), then 3-row combine ----
    float* E = (float*)smem;
    float bv[NNT];
    #pragma unroll
    for (int j = 0; j < NNT; ++j)
        bv[j] = bias[n0 + wn*WTN + j*16 + l16];

    #pragma unroll
    for (int i = 0; i < NMT; ++i) {
        int row_base = wm*WTM + i*16 + quad*4;
        #pragma unroll
        for (int j = 0; j < NNT; ++j) {
            int col = wn*WTN + j*16 + l16;
            #pragma unroll
            for (int r = 0; r < 4; ++r)
                E[(size_t)(row_base + r)*(BN+4) + col] = elu_f(acc[i][j][r] + bv[j]);
        }
    }
    __syncthreads();

    const float4* E4 = (const float4*)smem;
    #pragma unroll
    for (int e = tid; e < P*C4; e += 256) {
        int ul = e / C4;
        int c4 = e - ul*C4;
        int pu = pu0 + ul;
        int u  = pu & vmask_out;
        const float* w = dwt + u*3;
        float4 a0 = E4[(size_t)(ul*3 + 0)*(C4+1) + c4];
        float4 a1 = E4[(size_t)(ul*3 + 1)*(C4+1) + c4];
        float4 a2 = E4[(size_t)(ul*3 + 2)*(C4+1) + c4];
        float4 o;
        o.x = w[0]*a0.x + w[1]*a1.x + w[2]*a2.x;
        o.y = w[0]*a0.y + w[1]*a1.y + w[2]*a2.y;
        o.z = w[0]*a0.z + w[1]*a1.z + w[2]*a2.z;
        o.w = w[0]*a0.w + w[1]*a1.w + w[2]*a2.w;
        *(float4*)&out[(size_t)pu*C_OUT + n0 + c4*4] = o;
    }
}

// ---------------- fused conv0+pool0 (C_IN=3 padded to 4, K=36->64) ----------------
// P=128 pooled vertices, R=384 conv rows, BN=C_OUT=32, single K-tile.
__global__ __launch_bounds__(256)
void conv0_pool_mfma(const float* __restrict__ x, const int* __restrict__ spiral,
                     const _Float16* __restrict__ Wp, const float* __restrict__ bias,
                     const int* __restrict__ didx, const float* __restrict__ dwt,
                     float* __restrict__ out)
{
    constexpr int P = 128, R = 384, BN = 32;
    constexpr int NMT = 6, NNT = 2;        // 4 waves x (96 rows, 32 cols)
    constexpr int C4 = BN/4;
    constexpr int STAGE_B = 64*R*2 + 64*BN*2;   // 49152 + 4096
    constexpr int EPI_B   = R*(BN+4)*4;         // 55296
    constexpr int SMEM_B  = STAGE_B > EPI_B ? STAGE_B : EPI_B;
    __shared__ char smem[SMEM_B] __attribute__((aligned(16)));
    _Float16* As = (_Float16*)smem;
    _Float16* Ws = As + 64*R;

    const int tid  = threadIdx.x;
    const int wave = tid >> 6;
    const int lane = tid & 63;
    const int quad = lane >> 4;
    const int l16  = lane & 15;
    const int pu0  = blockIdx.x * P;

    f32x4 acc[NMT][NNT];
    #pragma unroll
    for (int i = 0; i < NMT; ++i)
        #pragma unroll
        for (int j = 0; j < NNT; ++j) acc[i][j] = (f32x4){0.f, 0.f, 0.f, 0.f};

    // ---- stage A: chunks 0..5 = spiral pairs (3 reals + pad), 6..7 = zero ----
    #pragma unroll
    for (int e = tid; e < R*8; e += 256) {
        int r  = e >> 3;
        int kc = e & 7;
        f16x8 h = (f16x8){0,0,0,0,0,0,0,0};
        if (kc < 6) {
            int ul = r / 3;
            int kp = r - ul*3;
            int pu = pu0 + ul;
            int b  = pu >> 13;
            int u  = pu & 8191;
            int v  = didx[u*3 + kp];
            int g0 = spiral[v*12 + kc*2];
            int g1 = spiral[v*12 + kc*2 + 1];
            const float* q0 = x + (size_t)(((size_t)b << 15) + g0)*3;
            const float* q1 = x + (size_t)(((size_t)b << 15) + g1)*3;
            h[0] = (_Float16)q0[0]; h[1] = (_Float16)q0[1]; h[2] = (_Float16)q0[2];
            h[4] = (_Float16)q1[0]; h[5] = (_Float16)q1[1]; h[6] = (_Float16)q1[2];
        }
        *(f16x8*)&As[(kc*R + r)*8] = h;
    }
    if (tid < 256) {
        *(f16x8*)&Ws[tid*8] = *(const f16x8*)&Wp[tid*8];
    }
    __syncthreads();

    #pragma unroll
    for (int kt = 0; kt < 2; ++kt) {
        f16x8 af[NMT], bf[NNT];
        #pragma unroll
        for (int i = 0; i < NMT; ++i) {
            int m_local = wave*96 + i*16 + l16;
            af[i] = *(const f16x8*)&As[((kt*4 + quad)*R + m_local)*8];
        }
        #pragma unroll
        for (int j = 0; j < NNT; ++j) {
            int n_local = j*16 + l16;
            bf[j] = *(const f16x8*)&Ws[((kt*4 + quad)*BN + n_local)*8];
        }
        #pragma unroll
        for (int i = 0; i < NMT; ++i)
            #pragma unroll
            for (int j = 0; j < NNT; ++j)
                acc[i][j] = __builtin_amdgcn_mfma_f32_16x16x32_f16(
                    af[i], bf[j], acc[i][j], 0, 0, 0);
    }
    __syncthreads();

    float* E = (float*)smem;
    float bv[NNT];
    #pragma unroll
    for (int j = 0; j < NNT; ++j) bv[j] = bias[j*16 + l16];

    #pragma unroll
    for (int i = 0; i < NMT; ++i) {
        int row_base = wave*96 + i*16 + quad*4;
        #pragma unroll
        for (int j = 0; j < NNT; ++j) {
            int col = j*16 + l16;
            #pragma unroll
            for (int r = 0; r < 4; ++r)
                E[(size_t)(row_base + r)*(BN+4) + col] = elu_f(acc[i][j][r] + bv[j]);
        }
    }
    __syncthreads();

    const float4* E4 = (const float4*)smem;
    #pragma unroll
    for (int e = tid; e < P*C4; e += 256) {
        int ul = e / C4;
        int c4 = e - ul*C4;
        int pu = pu0 + ul;
        int u  = pu & 8191;
        const float* w = dwt + u*3;
        float4 a0 = E4[(size_t)(ul*3 + 0)*(C4+1) + c4];
        float4 a1 = E4[(size_t)(ul*3 + 1)*(C4+1) + c4];
        float4 a2 = E4[(size_t)(ul*3 + 2)*(C4+1) + c4];
        float4 o;
        o.x = w[0]*a0.x + w[1]*a1.x + w[2]*a2.x;
        o.y = w[0]*a0.y + w[1]*a1.y + w[2]*a2.y;
        o.z = w[0]*a0.z + w[1]*a1.z + w[2]*a2.z;
        o.w = w[0]*a0.w + w[1]*a1.w + w[2]*a2.w;
        *(float4*)&out[(size_t)pu*BN + c4*4] = o;
    }
}

// ---------------- FC1 split-K + finish, FC2 ----------------
__global__ __launch_bounds__(256)
void fc1_partial(const float* __restrict__ xflat, const float* __restrict__ Wl1,
                 float* __restrict__ acc_out)
{
    __shared__ float xs[32][68];
    const int tid = threadIdx.x;
    const int n  = blockIdx.x * 64 + (tid & 63);
    const int mg = tid >> 6;
    const int kbase = blockIdx.y * 512;

    float acc[8];
    #pragma unroll
    for (int i = 0; i < 8; ++i) acc[i] = 0.0f;

    for (int kt = 0; kt < 512; kt += 64) {
        for (int e = tid; e < 32*64; e += 256) {
            int m = e >> 6, k = e & 63;
            xs[m][k] = xflat[(size_t)m*32768 + kbase + kt + k];
        }
        __syncthreads();
        for (int k = 0; k < 64; k += 4) {
            float wv[4];
            #pragma unroll
            for (int j = 0; j < 4; ++j)
                wv[j] = Wl1[(size_t)(kbase + kt + k + j)*512 + n];
            #pragma unroll
            for (int i = 0; i < 8; ++i) {
                float4 xv = *(const float4*)&xs[mg*8 + i][k];
                acc[i] += xv.x*wv[0] + xv.y*wv[1] + xv.z*wv[2] + xv.w*wv[3];
            }
        }
        __syncthreads();
    }
    #pragma unroll
    for (int i = 0; i < 8; ++i)
        atomicAdd(&acc_out[(size_t)(mg*8 + i)*512 + n], acc[i]);
}

__global__ __launch_bounds__(256)
void fc1_finish(const float* __restrict__ acc, const float* __restrict__ bl1,
                float* __restrict__ hout)
{
    int i = blockIdx.x * blockDim.x + threadIdx.x;
    float t = acc[i] + bl1[i & 511];
    hout[i] = elu_f(t);
}

__global__ __launch_bounds__(64)
void fc2_kernel(const float* __restrict__ h, const float* __restrict__ Wl2,
                const float* __restrict__ bl2, float* __restrict__ y)
{
    int m = blockIdx.x;
    int n = threadIdx.x;
    float s = bl2[n];
    for (int k = 0; k < 512; ++k)
        s += h[(size_t)m*512 + k] * Wl2[(size_t)k*64 + n];
    y[(size_t)m*64 + n] = s;
}

extern "C" void kernel_launch(void* const* d_in, const int* in_sizes, int n_in,
                              void* d_out, int out_size, void* d_ws, size_t ws_size,
                              hipStream_t stream)
{
    (void)in_sizes; (void)n_in; (void)out_size;

    const float* x0 = (const float*)d_in[0];
    const int*   sp[4]; const int* didx[4]; const float* dwp[4];
    const float* Wp[4]; const float* bp[4];
    for (int i = 0; i < 4; ++i) {
        sp[i]   = (const int*)  d_in[1 + i*5 + 0];
        didx[i] = (const int*)  d_in[1 + i*5 + 1];
        dwp[i]  = (const float*)d_in[1 + i*5 + 2];
        Wp[i]   = (const float*)d_in[1 + i*5 + 3];
        bp[i]   = (const float*)d_in[1 + i*5 + 4];
    }
    const float* Wl1 = (const float*)d_in[21];
    const float* bl1 = (const float*)d_in[22];
    const float* Wl2 = (const float*)d_in[23];
    const float* bl2 = (const float*)d_in[24];
    float* out = (float*)d_out;

    float* ws = (float*)d_ws;
    float* persist  = ws;                         // 1,048,576 floats: (32,128,256)
    float* fc1_acc  = ws + 1048576;               // 16,384 floats
    _Float16* w0h   = (_Float16*)(ws + 1048576 + 16384);  //   2,048 halfs
    _Float16* w1h   = w0h + 2048;                         //  24,576 halfs
    _Float16* w2h   = w1h + 24576;                        //  98,304 halfs
    _Float16* w3h   = w2h + 98304;                        // 393,216 halfs
    float* bufs     = ws + 1048576 + 16384 + 259072;

    // per-chunk pooled buffers: p0 Bc*262144, p1 Bc*131072, p2 Bc*65536 floats
    size_t avail_floats = ws_size / 4;
    const size_t fixed = 1048576 + 16384 + 259072;
    int Bc = 32;
    while (Bc > 1 && fixed + (size_t)Bc*458752ULL > avail_floats)
        Bc >>= 1;
    float* pooled0 = bufs;
    float* pooled1 = pooled0 + (size_t)Bc*262144ULL;
    float* pooled2 = pooled1 + (size_t)Bc*131072ULL;

    // Per-launch weight prep (fp32 -> fp16, tiled into LDS order)
    prep_w0<<<8, 256, 0, stream>>>(Wp[0], w0h);
    prep_w< 384,  64,  64><<<( 24576 + 255)/256, 256, 0, stream>>>(Wp[1], w1h);
    prep_w< 768, 128, 128><<<( 98304 + 255)/256, 256, 0, stream>>>(Wp[2], w2h);
    prep_w<1536, 256, 128><<<(393216 + 255)/256, 256, 0, stream>>>(Wp[3], w3h);

    hipMemsetAsync(fc1_acc, 0, 16384*sizeof(float), stream);

    for (int b0 = 0; b0 < 32; b0 += Bc) {
        const float* xin = x0 + (size_t)b0*32768*3;

        // L0: conv(3->32, K=36 padded 64) + pool -> (Bc, 8192, 32)
        conv0_pool_mfma<<<Bc*8192/128, 256, 0, stream>>>(
            xin, sp[0], w0h, bp[0], didx[0], dwp[0], pooled0);

        // L1: conv(32->64, K=384) + pool -> (Bc, 2048, 64)
        conv_pool_mfma<32,64,64,64,4,1><<<Bc*2048/64, 256, 0, stream>>>(
            pooled0, sp[1], w1h, bp[1], didx[1], dwp[1], pooled1, 13, 11);

        // L2: conv(64->128, K=768) + pool -> (Bc, 512, 128)
        conv_pool_mfma<64,128,32,128,2,2><<<Bc*512/32, 256, 0, stream>>>(
            pooled1, sp[2], w2h, bp[2], didx[2], dwp[2], pooled2, 11, 9);

        // L3: conv(128->256, K=1536) + pool -> persist chunk (Bc, 128, 256)
        conv_pool_mfma<128,256,32,128,2,2><<<dim3(Bc*128/32, 2), 256, 0, stream>>>(
            pooled2, sp[3], w3h, bp[3], didx[3], dwp[3],
            persist + (size_t)b0*32768, 9, 7);
    }

    // FC1: (32, 32768) @ (32768, 512) + bias, ELU -> d_out[0:16384]
    fc1_partial<<<dim3(8, 64), 256, 0, stream>>>(persist, Wl1, fc1_acc);
    fc1_finish<<<64, 256, 0, stream>>>(fc1_acc, bl1, out);

    // FC2: (32, 512) @ (512, 64) + bias -> d_out[16384:18432]
    fc2_kernel<<<32, 64, 0, stream>>>(out, Wl2, bl2, out + 16384);
}